// Round 1
// baseline (355.902 us; speedup 1.0000x reference)
//
#include <hip/hip_runtime.h>

typedef __attribute__((ext_vector_type(8))) short bf16x8;
typedef __attribute__((ext_vector_type(4))) float f32x4;
typedef __attribute__((ext_vector_type(4))) unsigned int u32x4;
typedef __attribute__((ext_vector_type(4))) float f32x4v;

#define MFMA16(a,b,c) __builtin_amdgcn_mfma_f32_16x16x32_bf16((a),(b),(c),0,0,0)

__device__ __forceinline__ short f2bf(float f){
  unsigned u = __builtin_bit_cast(unsigned, f);
  u += 0x7fffu + ((u >> 16) & 1u);   // round-to-nearest-even
  return (short)(u >> 16);
}

__device__ __forceinline__ void gload16(const void* g, void* l){
  __builtin_amdgcn_global_load_lds((const __attribute__((address_space(1))) unsigned*)g,
                                   (__attribute__((address_space(3))) unsigned*)l,
                                   16, 0, 0);
}

// ---------------- fp32 -> bf16 elementwise convert (vectorized) ----------------
__global__ __launch_bounds__(256) void k_f2bf(const float* __restrict__ in,
                                              short* __restrict__ out, int n8){
  int i = blockIdx.x * 256 + threadIdx.x;
  if (i >= n8) return;
  f32x4v a = ((const f32x4v*)in)[i*2];
  f32x4v b = ((const f32x4v*)in)[i*2+1];
  bf16x8 o;
  o[0]=f2bf(a[0]); o[1]=f2bf(a[1]); o[2]=f2bf(a[2]); o[3]=f2bf(a[3]);
  o[4]=f2bf(b[0]); o[5]=f2bf(b[1]); o[6]=f2bf(b[2]); o[7]=f2bf(b[3]);
  ((bf16x8*)out)[i] = o;
}

// ---------------- weight transpose + convert: Wt[n][k] = bf16(W[k][n]) ----------------
__global__ __launch_bounds__(256) void k_prep_wT(const float* __restrict__ W,
                                                 short* __restrict__ Wt, int K, int N){
  int i = blockIdx.x * 256 + threadIdx.x;
  int total = (K >> 3) * N;
  if (i >= total) return;
  int n  = i % N;
  int k0 = (i / N) << 3;
  bf16x8 o;
#pragma unroll
  for (int j = 0; j < 8; ++j) o[j] = f2bf(W[(size_t)(k0 + j) * N + n]);
  *(bf16x8*)&Wt[(size_t)n * K + k0] = o;
}

// ---------------- V transpose: V[bh][2048][128] -> Vt[bh][128][2048] ----------------
__global__ __launch_bounds__(256) void k_transpose_v(const short* __restrict__ V,
                                                     short* __restrict__ Vt){
  int bh = blockIdx.y;
  int n0 = blockIdx.x * 64;
  int tid = threadIdx.x;
  int n = n0 + (tid & 63);
  int dhg = (tid >> 6) * 8;
  const short* vbase = V  + (size_t)bh * 2048 * 128;
  short*       tbase = Vt + (size_t)bh * 128 * 2048;
#pragma unroll
  for (int p = 0; p < 4; ++p){
    int dh0 = p * 32 + dhg;
    bf16x8 v = *(const bf16x8*)&vbase[(size_t)n * 128 + dh0];
#pragma unroll
    for (int j = 0; j < 8; ++j)
      tbase[(size_t)(dh0 + j) * 2048 + n] = v[j];   // lanes 0..63 -> contiguous 128B
  }
}

// ---------------- 128x128-tile bf16 GEMM, C = A @ Bt^T, fused epilogues ----------------
// A: [M][K] bf16 row-major, Bt: [N][K] bf16 (pre-transposed weights).
// MODE 0: Q proj  -> out0 = Qb bf16 [b][h][l][dh] with the reference's DIRECT reshape:
//                   h = l'>>7, l = ((l'&127)<<3)|(d'>>7), dh = d'&127
// MODE 1: KV proj -> out0 = K bf16 [b][h][n][dh], out1 = V bf16 [b][h][n][dh]
// MODE 2: out proj-> out0 = fp32 d_out [row][col]
template<int MODE>
__global__ __launch_bounds__(256, 2) void k_gemm(
    const short* __restrict__ A, const short* __restrict__ Bt,
    const float* __restrict__ bias, float scale,
    void* __restrict__ out0, void* __restrict__ out1,
    int M, int N, int K)
{
  __shared__ __align__(16) short Alds[2][128 * 32];
  __shared__ __align__(16) short Blds[2][128 * 32];
  const int tid = threadIdx.x;
  const int l = tid & 63, w = tid >> 6;
  const int m0 = blockIdx.y * 128, n0 = blockIdx.x * 128;
  const int wr = w >> 1, wc = w & 1;
  const int lr = l & 15, lg = l >> 4;

  // staging geometry: 16 chunks of 1KB (A:0..7, B:8..15); wave w issues chunks w*4..w*4+3
  const int srow = l >> 2;                      // row within 16-row chunk
  const int scol = 8 * ((l & 3) ^ (srow & 3));  // pre-swizzled source k-offset (elems)
  // read-side swizzle: element col = 8*(lg ^ (row&3)); row&3 == lr&3 for our rows
  const int acol = 8 * (lg ^ (lr & 3));

  f32x4 acc[4][4];
#pragma unroll
  for (int a = 0; a < 4; ++a)
#pragma unroll
    for (int b = 0; b < 4; ++b) acc[a][b] = (f32x4)(0.0f);

  const int nk = K >> 5;
  auto stage = [&](int kt, int buf){
    int k0 = kt << 5;
#pragma unroll
    for (int i = 0; i < 4; ++i){
      int c = w * 4 + i;
      if (c < 8){
        int m = c * 16 + srow;
        gload16(A + (size_t)(m0 + m) * K + k0 + scol, &Alds[buf][c * 512]);
      } else {
        int n = (c - 8) * 16 + srow;
        gload16(Bt + (size_t)(n0 + n) * K + k0 + scol, &Blds[buf][(c - 8) * 512]);
      }
    }
  };

  stage(0, 0);
  __syncthreads();
  int cur = 0;
  for (int kt = 0; kt < nk; ++kt){
    if (kt + 1 < nk) stage(kt + 1, cur ^ 1);
    bf16x8 af[4], bfv[4];
#pragma unroll
    for (int mi = 0; mi < 4; ++mi){
      int row = wr * 64 + mi * 16 + lr;
      af[mi] = *(const bf16x8*)&Alds[cur][row * 32 + acol];
    }
#pragma unroll
    for (int ni = 0; ni < 4; ++ni){
      int row = wc * 64 + ni * 16 + lr;
      bfv[ni] = *(const bf16x8*)&Blds[cur][row * 32 + acol];
    }
#pragma unroll
    for (int mi = 0; mi < 4; ++mi)
#pragma unroll
      for (int ni = 0; ni < 4; ++ni)
        acc[mi][ni] = MFMA16(af[mi], bfv[ni], acc[mi][ni]);
    __syncthreads();
    cur ^= 1;
  }

  // epilogue
#pragma unroll
  for (int mi = 0; mi < 4; ++mi)
#pragma unroll
    for (int ni = 0; ni < 4; ++ni){
      int col = n0 + wc * 64 + ni * 16 + lr;
      float bv = bias[col];
#pragma unroll
      for (int r = 0; r < 4; ++r){
        int row = m0 + wr * 64 + mi * 16 + lg * 4 + r;
        float v = acc[mi][ni][r] + bv;
        if (MODE == 0){
          v *= scale;
          int b = row >> 10, lp = row & 1023;
          int h = lp >> 7;
          int lq = ((lp & 127) << 3) | (col >> 7);
          int dh = col & 127;
          ((short*)out0)[(((size_t)(b * 8 + h)) * 1024 + lq) * 128 + dh] = f2bf(v);
        } else if (MODE == 1){
          int b = row >> 11, nn = row & 2047;
          if (col < 1024){
            int h = col >> 7, dh = col & 127;
            ((short*)out0)[(((size_t)(b * 8 + h)) * 2048 + nn) * 128 + dh] = f2bf(v);
          } else {
            int c2 = col - 1024, h = c2 >> 7, dh = c2 & 127;
            ((short*)out1)[(((size_t)(b * 8 + h)) * 2048 + nn) * 128 + dh] = f2bf(v);
          }
        } else {
          ((float*)out0)[(size_t)row * N + col] = v;
        }
      }
    }
}

// ---------------- flash attention: Q[bh][1024][128], K[bh][2048][128], Vt[bh][128][2048]
// logits already in log2 units (log2e folded into Q scale); online softmax.
// Output written with the reference's direct (bs,H,L,Dh)->(bs,L,D) reshape.
__global__ __launch_bounds__(256, 2) void k_attn(
    const short* __restrict__ Q, const short* __restrict__ K,
    const short* __restrict__ Vt, short* __restrict__ O)
{
  __shared__ __align__(16) short Klds[64][136];   // [key][dh], +8 pad
  __shared__ __align__(16) short Vlds[128][72];   // [dh][key], +8 pad
  __shared__ __align__(16) short Plds[4][16][72]; // per-wave P, [qrow][key], +8 pad
  const int tid = threadIdx.x;
  const int l = tid & 63, w = tid >> 6;
  const int bh = blockIdx.y;
  const int q0 = blockIdx.x * 64;
  const int lr = l & 15, lg = l >> 4;

  const short* Qb = Q  + (size_t)bh * 1024 * 128;
  const short* Kb = K  + (size_t)bh * 2048 * 128;
  const short* Vb = Vt + (size_t)bh * 128 * 2048;

  // hoist Q fragments (A operand: row = lr, k = kc*32 + lg*8 + e)
  const int qrow = q0 + w * 16 + lr;
  bf16x8 qf[4];
#pragma unroll
  for (int kc = 0; kc < 4; ++kc)
    qf[kc] = *(const bf16x8*)&Qb[(size_t)qrow * 128 + kc * 32 + lg * 8];

  f32x4 acc[8];
#pragma unroll
  for (int d = 0; d < 8; ++d) acc[d] = (f32x4)(0.0f);
  float mrun[4], lrun[4];
#pragma unroll
  for (int r = 0; r < 4; ++r){ mrun[r] = -3e38f; lrun[r] = 0.f; }

  u32x4 kreg[4], vreg[4];
  auto loadregs = [&](int t){
    int kv0 = t * 64;
#pragma unroll
    for (int p = 0; p < 4; ++p){
      kreg[p] = *(const u32x4*)&Kb[(size_t)(kv0 + p * 16 + (tid >> 4)) * 128 + (tid & 15) * 8];
      vreg[p] = *(const u32x4*)&Vb[(size_t)(p * 32 + (tid >> 3)) * 2048 + kv0 + (tid & 7) * 8];
    }
  };
  auto writelds = [&](){
#pragma unroll
    for (int p = 0; p < 4; ++p){
      *(u32x4*)&Klds[p * 16 + (tid >> 4)][(tid & 15) * 8] = kreg[p];
      *(u32x4*)&Vlds[p * 32 + (tid >> 3)][(tid & 7) * 8] = vreg[p];
    }
  };

  loadregs(0);
  for (int t = 0; t < 32; ++t){
    __syncthreads();               // previous tile's LDS reads done
    writelds();
    __syncthreads();               // staged tile visible
    if (t + 1 < 32) loadregs(t + 1);   // prefetch overlaps compute

    // S = Q K^T (log2 units); S frag nt: rows = lg*4+r (query), col = lr (key)
    f32x4 s[4];
#pragma unroll
    for (int nt = 0; nt < 4; ++nt){
      f32x4 sv = (f32x4)(0.0f);
#pragma unroll
      for (int kc = 0; kc < 4; ++kc){
        bf16x8 kf = *(const bf16x8*)&Klds[nt * 16 + lr][kc * 32 + lg * 8];
        sv = MFMA16(qf[kc], kf, sv);
      }
      s[nt] = sv;
    }

    // online softmax
    float mnew[4], sc[4], rsum[4];
#pragma unroll
    for (int r = 0; r < 4; ++r){
      float v = fmaxf(fmaxf(s[0][r], s[1][r]), fmaxf(s[2][r], s[3][r]));
      v = fmaxf(v, __shfl_xor(v, 1, 16));
      v = fmaxf(v, __shfl_xor(v, 2, 16));
      v = fmaxf(v, __shfl_xor(v, 4, 16));
      v = fmaxf(v, __shfl_xor(v, 8, 16));
      mnew[r] = fmaxf(mrun[r], v);
      sc[r] = exp2f(mrun[r] - mnew[r]);
      mrun[r] = mnew[r];
      rsum[r] = 0.f;
    }
#pragma unroll
    for (int nt = 0; nt < 4; ++nt)
#pragma unroll
      for (int r = 0; r < 4; ++r){
        float p = exp2f(s[nt][r] - mnew[r]);
        rsum[r] += p;
        Plds[w][lg * 4 + r][nt * 16 + lr] = f2bf(p);
      }
#pragma unroll
    for (int r = 0; r < 4; ++r){
      float rs = rsum[r];
      rs += __shfl_xor(rs, 1, 16);
      rs += __shfl_xor(rs, 2, 16);
      rs += __shfl_xor(rs, 4, 16);
      rs += __shfl_xor(rs, 8, 16);
      lrun[r] = lrun[r] * sc[r] + rs;
#pragma unroll
      for (int d = 0; d < 8; ++d) acc[d][r] *= sc[r];
    }

    // PV: A = P (row=lr, k=key), B = V (col=dh via lr, k=key)
    bf16x8 pa[2];
#pragma unroll
    for (int kc = 0; kc < 2; ++kc)
      pa[kc] = *(const bf16x8*)&Plds[w][lr][kc * 32 + lg * 8];
#pragma unroll
    for (int d = 0; d < 8; ++d)
#pragma unroll
      for (int kc = 0; kc < 2; ++kc){
        bf16x8 vf = *(const bf16x8*)&Vlds[d * 16 + lr][kc * 32 + lg * 8];
        acc[d] = MFMA16(pa[kc], vf, acc[d]);
      }
  }

  // epilogue: O[b][ h*128 + (l>>3) ][ (l&7)*128 + dh ]  (direct-reshape inverse)
  const int b = bh >> 3, h = bh & 7;
#pragma unroll
  for (int r = 0; r < 4; ++r){
    float inv = 1.0f / lrun[r];
    int grow = q0 + w * 16 + lg * 4 + r;           // attention-space l
    size_t base = ((size_t)b * 1024 + (size_t)h * 128 + (grow >> 3)) * 1024
                + (size_t)(grow & 7) * 128;
#pragma unroll
    for (int d = 0; d < 8; ++d)
      O[base + d * 16 + lr] = f2bf(acc[d][r] * inv);
  }
}

extern "C" void kernel_launch(void* const* d_in, const int* in_sizes, int n_in,
                              void* d_out, int out_size, void* d_ws, size_t ws_size,
                              hipStream_t stream){
  const float* motion = (const float*)d_in[0];
  const float* scene  = (const float*)d_in[1];
  const float* Wq     = (const float*)d_in[2];
  const float* bq     = (const float*)d_in[3];
  const float* Wkv    = (const float*)d_in[4];
  const float* bkv    = (const float*)d_in[5];
  const float* Wout   = (const float*)d_in[6];
  const float* bout   = (const float*)d_in[7];
  float* out = (float*)d_out;

  char* ws = (char*)d_ws;
  const size_t MB = 1024 * 1024;
  short* WqT   = (short*)(ws + 0);        // 2 MB
  short* WkvT  = (short*)(ws + 2  * MB);  // 4 MB
  short* WoutT = (short*)(ws + 6  * MB);  // 2 MB
  short* mA    = (short*)(ws + 8  * MB);  // 16 MB motion bf16 (reused as attnO)
  short* sA    = (short*)(ws + 24 * MB);  // 32 MB scene bf16 (reused as Vt)
  short* Qb    = (short*)(ws + 56 * MB);  // 16 MB
  short* Kb    = (short*)(ws + 72 * MB);  // 32 MB
  short* Vb    = (short*)(ws + 104* MB);  // 32 MB   (total 136 MB)
  short* attnO = mA;
  short* Vtb   = sA;

  const float qscale = 0.03125f * 1.44269504088896341f;  // D^-0.5 * log2(e)

  k_prep_wT<<<dim3(512),  256, 0, stream>>>(Wq,   WqT,   1024, 1024);
  k_prep_wT<<<dim3(1024), 256, 0, stream>>>(Wkv,  WkvT,  1024, 2048);
  k_prep_wT<<<dim3(512),  256, 0, stream>>>(Wout, WoutT, 1024, 1024);
  k_f2bf<<<dim3(4096), 256, 0, stream>>>(motion, mA, 1024 * 1024);
  k_f2bf<<<dim3(8192), 256, 0, stream>>>(scene,  sA, 2 * 1024 * 1024);

  k_gemm<0><<<dim3(8, 64),   256, 0, stream>>>(mA, WqT,  bq,  qscale, Qb, nullptr, 8192, 1024, 1024);
  k_gemm<1><<<dim3(16, 128), 256, 0, stream>>>(sA, WkvT, bkv, 1.0f,   Kb, Vb,     16384, 2048, 1024);
  k_transpose_v<<<dim3(32, 64), 256, 0, stream>>>(Vb, Vtb);
  k_attn<<<dim3(16, 64), 256, 0, stream>>>(Qb, Kb, Vtb, attnO);
  k_gemm<2><<<dim3(8, 64), 256, 0, stream>>>(attnO, WoutT, bout, 1.0f, out, nullptr, 8192, 1024, 1024);
}

// Round 2
// 345.055 us; speedup vs baseline: 1.0314x; 1.0314x over previous
//
#include <hip/hip_runtime.h>

typedef __attribute__((ext_vector_type(8))) short bf16x8;
typedef __attribute__((ext_vector_type(4))) float f32x4;
typedef __attribute__((ext_vector_type(4))) float f32x4v;

#define MFMA16(a,b,c) __builtin_amdgcn_mfma_f32_16x16x32_bf16((a),(b),(c),0,0,0)

__device__ __forceinline__ short f2bf(float f){
  unsigned u = __builtin_bit_cast(unsigned, f);
  u += 0x7fffu + ((u >> 16) & 1u);   // round-to-nearest-even
  return (short)(u >> 16);
}

__device__ __forceinline__ void gload16(const void* g, void* l){
  __builtin_amdgcn_global_load_lds((const __attribute__((address_space(1))) unsigned*)g,
                                   (__attribute__((address_space(3))) unsigned*)l,
                                   16, 0, 0);
}

// ---------------- fp32 -> bf16 elementwise convert (vectorized) ----------------
__global__ __launch_bounds__(256) void k_f2bf(const float* __restrict__ in,
                                              short* __restrict__ out, int n8){
  int i = blockIdx.x * 256 + threadIdx.x;
  if (i >= n8) return;
  f32x4v a = ((const f32x4v*)in)[i*2];
  f32x4v b = ((const f32x4v*)in)[i*2+1];
  bf16x8 o;
  o[0]=f2bf(a[0]); o[1]=f2bf(a[1]); o[2]=f2bf(a[2]); o[3]=f2bf(a[3]);
  o[4]=f2bf(b[0]); o[5]=f2bf(b[1]); o[6]=f2bf(b[2]); o[7]=f2bf(b[3]);
  ((bf16x8*)out)[i] = o;
}

// ---------------- weight transpose + convert: Wt[n][k] = bf16(W[k][n]) ----------------
__global__ __launch_bounds__(256) void k_prep_wT(const float* __restrict__ W,
                                                 short* __restrict__ Wt, int K, int N){
  int i = blockIdx.x * 256 + threadIdx.x;
  int total = (K >> 3) * N;
  if (i >= total) return;
  int n  = i % N;
  int k0 = (i / N) << 3;
  bf16x8 o;
#pragma unroll
  for (int j = 0; j < 8; ++j) o[j] = f2bf(W[(size_t)(k0 + j) * N + n]);
  *(bf16x8*)&Wt[(size_t)n * K + k0] = o;
}

// ---------------- 128x128-tile bf16 GEMM, C = A @ Bt^T, fused epilogues ----------------
// MODE 0: Q proj  -> Qb bf16 [b][h][l][dh] via the reference's DIRECT reshape
// MODE 1: KV proj -> out0 = K bf16 [bh][n][dh], out1 = V bf16 [bh][dh][n] (TRANSPOSED)
// MODE 2: out proj-> fp32 d_out
template<int MODE>
__global__ __launch_bounds__(256, 2) void k_gemm(
    const short* __restrict__ A, const short* __restrict__ Bt,
    const float* __restrict__ bias, float scale,
    void* __restrict__ out0, void* __restrict__ out1,
    int M, int N, int K)
{
  __shared__ __align__(16) short Alds[2][128 * 32];
  __shared__ __align__(16) short Blds[2][128 * 32];
  const int tid = threadIdx.x;
  const int l = tid & 63, w = tid >> 6;
  const int m0 = blockIdx.y * 128, n0 = blockIdx.x * 128;
  const int wr = w >> 1, wc = w & 1;
  const int lr = l & 15, lg = l >> 4;

  const int srow = l >> 2;
  const int scol = 8 * ((l & 3) ^ (srow & 3));
  const int acol = 8 * (lg ^ (lr & 3));

  f32x4 acc[4][4];
#pragma unroll
  for (int a = 0; a < 4; ++a)
#pragma unroll
    for (int b = 0; b < 4; ++b) acc[a][b] = (f32x4)(0.0f);

  const int nk = K >> 5;
  auto stage = [&](int kt, int buf){
    int k0 = kt << 5;
#pragma unroll
    for (int i = 0; i < 4; ++i){
      int c = w * 4 + i;
      if (c < 8){
        int m = c * 16 + srow;
        gload16(A + (size_t)(m0 + m) * K + k0 + scol, &Alds[buf][c * 512]);
      } else {
        int n = (c - 8) * 16 + srow;
        gload16(Bt + (size_t)(n0 + n) * K + k0 + scol, &Blds[buf][(c - 8) * 512]);
      }
    }
  };

  stage(0, 0);
  __syncthreads();
  int cur = 0;
  for (int kt = 0; kt < nk; ++kt){
    if (kt + 1 < nk) stage(kt + 1, cur ^ 1);
    bf16x8 af[4], bfv[4];
#pragma unroll
    for (int mi = 0; mi < 4; ++mi){
      int row = wr * 64 + mi * 16 + lr;
      af[mi] = *(const bf16x8*)&Alds[cur][row * 32 + acol];
    }
#pragma unroll
    for (int ni = 0; ni < 4; ++ni){
      int row = wc * 64 + ni * 16 + lr;
      bfv[ni] = *(const bf16x8*)&Blds[cur][row * 32 + acol];
    }
#pragma unroll
    for (int mi = 0; mi < 4; ++mi)
#pragma unroll
      for (int ni = 0; ni < 4; ++ni)
        acc[mi][ni] = MFMA16(af[mi], bfv[ni], acc[mi][ni]);
    __syncthreads();
    cur ^= 1;
  }

#pragma unroll
  for (int mi = 0; mi < 4; ++mi)
#pragma unroll
    for (int ni = 0; ni < 4; ++ni){
      int col = n0 + wc * 64 + ni * 16 + lr;
      float bv = bias[col];
#pragma unroll
      for (int r = 0; r < 4; ++r){
        int row = m0 + wr * 64 + mi * 16 + lg * 4 + r;
        float v = acc[mi][ni][r] + bv;
        if (MODE == 0){
          v *= scale;
          int b = row >> 10, lp = row & 1023;
          int h = lp >> 7;
          int lq = ((lp & 127) << 3) | (col >> 7);
          int dh = col & 127;
          ((short*)out0)[(((size_t)(b * 8 + h)) * 1024 + lq) * 128 + dh] = f2bf(v);
        } else if (MODE == 1){
          int b = row >> 11, nn = row & 2047;
          if (col < 1024){
            int h = col >> 7, dh = col & 127;
            ((short*)out0)[(((size_t)(b * 8 + h)) * 2048 + nn) * 128 + dh] = f2bf(v);
          } else {
            int c2 = col - 1024, h = c2 >> 7, dh = c2 & 127;
            // V written DIRECTLY transposed: [bh][dh][n]
            ((short*)out1)[(((size_t)(b * 8 + h)) * 128 + dh) * 2048 + nn] = f2bf(v);
          }
        } else {
          ((float*)out0)[(size_t)row * N + col] = v;
        }
      }
    }
}

// ---------------- flash attention ----------------
// Q[bh][1024][128], K[bh][2048][128], Vt[bh][128][2048]; logits in log2 units.
// 4 waves x 32 q-rows = 128 q/block; KVBLK=64, double-buffered, XOR-swizzled LDS.
__global__ __launch_bounds__(256, 2) void k_attn(
    const short* __restrict__ Q, const short* __restrict__ K,
    const short* __restrict__ Vt, short* __restrict__ O)
{
  __shared__ __align__(16) short Klds[2][64 * 128];   // [key][dh^swz], 16KB each
  __shared__ __align__(16) short Vlds[2][128 * 64];   // [dh][key^swz], 16KB each
  __shared__ __align__(16) short Plds[4][32 * 64];    // per-wave [q][key^swz], 4KB each
  const int tid = threadIdx.x;
  const int l = tid & 63, w = tid >> 6;
  const int lr = l & 15, lg = l >> 4;

  // XCD-chunked remap: each XCD owns 8 consecutive bh (K/V L2 locality)
  int flat = blockIdx.y * 8 + blockIdx.x;   // grid (8, 64), 512 blocks
  int xcd = flat & 7, idx = flat >> 3;
  int bh = xcd * 8 + (idx >> 3);
  int q0 = (idx & 7) * 128;

  const short* Qb = Q  + (size_t)bh * 1024 * 128;
  const short* Kb = K  + (size_t)bh * 2048 * 128;
  const short* Vb = Vt + (size_t)bh * 128 * 2048;

  // Q fragments (A operand): q = q0 + w*32 + mi*16 + lr, k = kc*32 + lg*8 + e
  bf16x8 qf[2][4];
#pragma unroll
  for (int mi = 0; mi < 2; ++mi)
#pragma unroll
    for (int kc = 0; kc < 4; ++kc)
      qf[mi][kc] = *(const bf16x8*)&Qb[(size_t)(q0 + w * 32 + mi * 16 + lr) * 128 + kc * 32 + lg * 8];

  f32x4 acc[8][2];
#pragma unroll
  for (int d = 0; d < 8; ++d){ acc[d][0] = (f32x4)(0.0f); acc[d][1] = (f32x4)(0.0f); }
  float mrun[2][4], lsum[2][4];
#pragma unroll
  for (int mi = 0; mi < 2; ++mi)
#pragma unroll
    for (int r = 0; r < 4; ++r){ mrun[mi][r] = -3e38f; lsum[mi][r] = 0.f; }

  // staging: pre-swizzled global source + linear LDS dest (swizzle involution)
  auto stageK = [&](int t, int buf){
    int kv0 = t * 64;
#pragma unroll
    for (int i = 0; i < 4; ++i){
      int c = w * 4 + i;
      int row = 4 * c + (l >> 4);
      int col = ((l & 15) * 8) ^ ((row & 7) * 8);
      gload16(Kb + (size_t)(kv0 + row) * 128 + col, &Klds[buf][c * 512]);
    }
  };
  auto stageV = [&](int t, int buf){
    int kv0 = t * 64;
#pragma unroll
    for (int i = 0; i < 4; ++i){
      int c = w * 4 + i;
      int dh = 8 * c + (l >> 3);
      int col = ((l & 7) * 8) ^ (((l >> 3) & 7) * 8);
      gload16(Vb + (size_t)dh * 2048 + kv0 + col, &Vlds[buf][c * 512]);
    }
  };

  stageK(0, 0); stageV(0, 0);
  __syncthreads();
  int cur = 0;
  const int swz = (lr & 7) * 8;

  for (int t = 0; t < 32; ++t){
    if (t + 1 < 32){ stageK(t + 1, cur ^ 1); stageV(t + 1, cur ^ 1); }
    const short* Kl = &Klds[cur][0];
    const short* Vl = &Vlds[cur][0];
    short* Pw = &Plds[w][0];

    // ---- QK^T: S[q, key]; lane holds key=nt*16+lr, q=mi*16+lg*4+r
    f32x4 s[2][4];
#pragma unroll
    for (int nt = 0; nt < 4; ++nt){
      f32x4 s0 = (f32x4)(0.0f), s1 = (f32x4)(0.0f);
#pragma unroll
      for (int kc = 0; kc < 4; ++kc){
        bf16x8 kf = *(const bf16x8*)&Kl[(nt * 16 + lr) * 128 + ((kc * 32 + lg * 8) ^ swz)];
        s0 = MFMA16(qf[0][kc], kf, s0);
        s1 = MFMA16(qf[1][kc], kf, s1);
      }
      s[0][nt] = s0; s[1][nt] = s1;
    }

    // ---- defer-max online softmax (log2 units, THR=8)
    float pmax[2][4];
    int ok = 1;
#pragma unroll
    for (int mi = 0; mi < 2; ++mi)
#pragma unroll
      for (int r = 0; r < 4; ++r){
        float v = fmaxf(fmaxf(s[mi][0][r], s[mi][1][r]), fmaxf(s[mi][2][r], s[mi][3][r]));
        pmax[mi][r] = v;
        ok &= (v <= mrun[mi][r] + 8.0f) ? 1 : 0;
      }
    if (!__all(ok)){
#pragma unroll
      for (int mi = 0; mi < 2; ++mi)
#pragma unroll
        for (int r = 0; r < 4; ++r){
          float v = pmax[mi][r];
          v = fmaxf(v, __shfl_xor(v, 1, 16));
          v = fmaxf(v, __shfl_xor(v, 2, 16));
          v = fmaxf(v, __shfl_xor(v, 4, 16));
          v = fmaxf(v, __shfl_xor(v, 8, 16));
          float mnew = fmaxf(mrun[mi][r], v);
          float sc = exp2f(mrun[mi][r] - mnew);
          mrun[mi][r] = mnew;
          lsum[mi][r] *= sc;
#pragma unroll
          for (int d = 0; d < 8; ++d) acc[d][mi][r] *= sc;
        }
    }

    // ---- P = exp2(S - mrun), per-lane partial sums, write P to LDS (swizzled)
#pragma unroll
    for (int mi = 0; mi < 2; ++mi)
#pragma unroll
      for (int r = 0; r < 4; ++r){
        int row = mi * 16 + lg * 4 + r;
        int rsw = (row & 7) * 8;
        float ls = 0.f;
#pragma unroll
        for (int nt = 0; nt < 4; ++nt){
          float p = exp2f(s[mi][nt][r] - mrun[mi][r]);
          ls += p;
          Pw[row * 64 + ((nt * 16 + lr) ^ rsw)] = f2bf(p);
        }
        lsum[mi][r] += ls;
      }

    // ---- PV: A = P (row=q), B = V^T (col=dh)
    bf16x8 pa[2][2];
#pragma unroll
    for (int mi = 0; mi < 2; ++mi)
#pragma unroll
      for (int kc = 0; kc < 2; ++kc)
        pa[mi][kc] = *(const bf16x8*)&Pw[(mi * 16 + lr) * 64 + ((kc * 32 + lg * 8) ^ swz)];
#pragma unroll
    for (int d = 0; d < 8; ++d)
#pragma unroll
      for (int kc = 0; kc < 2; ++kc){
        bf16x8 vf = *(const bf16x8*)&Vl[(d * 16 + lr) * 64 + ((kc * 32 + lg * 8) ^ swz)];
        acc[d][0] = MFMA16(pa[0][kc], vf, acc[d][0]);
        acc[d][1] = MFMA16(pa[1][kc], vf, acc[d][1]);
      }

    __syncthreads();
    cur ^= 1;
  }

  // ---- epilogue: reduce lsum across the 16 key-lanes, scale, store
  const int b = bh >> 3, h = bh & 7;
#pragma unroll
  for (int mi = 0; mi < 2; ++mi)
#pragma unroll
    for (int r = 0; r < 4; ++r){
      float ls = lsum[mi][r];
      ls += __shfl_xor(ls, 1, 16);
      ls += __shfl_xor(ls, 2, 16);
      ls += __shfl_xor(ls, 4, 16);
      ls += __shfl_xor(ls, 8, 16);
      float inv = 1.0f / ls;
      int grow = q0 + w * 32 + mi * 16 + lg * 4 + r;
      size_t base = ((size_t)b * 1024 + (size_t)h * 128 + (grow >> 3)) * 1024
                  + (size_t)(grow & 7) * 128;
#pragma unroll
      for (int d = 0; d < 8; ++d)
        O[base + d * 16 + lr] = f2bf(acc[d][mi][r] * inv);
    }
}

extern "C" void kernel_launch(void* const* d_in, const int* in_sizes, int n_in,
                              void* d_out, int out_size, void* d_ws, size_t ws_size,
                              hipStream_t stream){
  const float* motion = (const float*)d_in[0];
  const float* scene  = (const float*)d_in[1];
  const float* Wq     = (const float*)d_in[2];
  const float* bq     = (const float*)d_in[3];
  const float* Wkv    = (const float*)d_in[4];
  const float* bkv    = (const float*)d_in[5];
  const float* Wout   = (const float*)d_in[6];
  const float* bout   = (const float*)d_in[7];
  float* out = (float*)d_out;

  char* ws = (char*)d_ws;
  const size_t MB = 1024 * 1024;
  short* WqT   = (short*)(ws + 0);        // 2 MB
  short* WkvT  = (short*)(ws + 2  * MB);  // 4 MB
  short* WoutT = (short*)(ws + 6  * MB);  // 2 MB
  short* mA    = (short*)(ws + 8  * MB);  // 16 MB motion bf16 (reused as attnO)
  short* sA    = (short*)(ws + 24 * MB);  // 32 MB scene bf16
  short* Qb    = (short*)(ws + 56 * MB);  // 16 MB
  short* Kb    = (short*)(ws + 72 * MB);  // 32 MB
  short* Vtb   = (short*)(ws + 104* MB);  // 32 MB  V already transposed [bh][dh][n]
  short* attnO = mA;

  const float qscale = 0.03125f * 1.44269504088896341f;  // D^-0.5 * log2(e)

  k_prep_wT<<<dim3(512),  256, 0, stream>>>(Wq,   WqT,   1024, 1024);
  k_prep_wT<<<dim3(1024), 256, 0, stream>>>(Wkv,  WkvT,  1024, 2048);
  k_prep_wT<<<dim3(512),  256, 0, stream>>>(Wout, WoutT, 1024, 1024);
  k_f2bf<<<dim3(4096), 256, 0, stream>>>(motion, mA, 1024 * 1024);
  k_f2bf<<<dim3(8192), 256, 0, stream>>>(scene,  sA, 2 * 1024 * 1024);

  k_gemm<0><<<dim3(8, 64),   256, 0, stream>>>(mA, WqT,  bq,  qscale, Qb, nullptr, 8192, 1024, 1024);
  k_gemm<1><<<dim3(16, 128), 256, 0, stream>>>(sA, WkvT, bkv, 1.0f,   Kb, Vtb,    16384, 2048, 1024);
  k_attn<<<dim3(8, 64), 256, 0, stream>>>(Qb, Kb, Vtb, attnO);
  k_gemm<2><<<dim3(8, 64), 256, 0, stream>>>(attnO, WoutT, bout, 1.0f, out, nullptr, 8192, 1024, 1024);
}